// Round 16
// baseline (964.036 us; speedup 1.0000x reference)
//
#include <hip/hip_runtime.h>

#define NB 8
#define NS 1024
#define ND 768
#define NH 12
#define NHD 64
#define NLAYERS 12
#define NM (NB * NS)   // 8192 rows
#define NQKV3 (3 * ND) // 2304 output cols of fused QKV GEMM
#define QSCALE 0.1803368802f  // (1/8) * log2(e): softmax runs in exp2 domain

typedef _Float16 f16;
typedef _Float16 f16x8 __attribute__((ext_vector_type(8)));
typedef _Float16 f16x4 __attribute__((ext_vector_type(4)));
typedef _Float16 f16x2 __attribute__((ext_vector_type(2)));
typedef float f32x4 __attribute__((ext_vector_type(4)));
typedef float f32x16 __attribute__((ext_vector_type(16)));
typedef unsigned int u32x4 __attribute__((ext_vector_type(4)));

__device__ inline float fexp2(float x) {
  float r;
  asm("v_exp_f32 %0, %1" : "=v"(r) : "v"(x));
  return r;
}

// async global->LDS DMA, 16B per lane; LDS dest = wave-uniform base + lane*16
__device__ __forceinline__ void gload16(const void* g, void* l) {
  __builtin_amdgcn_global_load_lds(
      (const __attribute__((address_space(1))) void*)g,
      (__attribute__((address_space(3))) void*)l, 16, 0, 0);
}

// ---------------------------------------------------------------------------
// One-time weight prep.
//  Wcat[n][d] (f16, B^T layout), n = sel*768 + h*64 + kp:
//    sel 0: Wq[h][d][kp]   sel 1: Wk[h][d][kp]   sel 2: (Wv@Wo)[h][d][kp]
//  bvo[h*64+j] = sum_m bv[h][m]*Wo[h][m][j] + bo[h][j]
// ---------------------------------------------------------------------------
__global__ __launch_bounds__(256) void prep_weights(
    const float* __restrict__ Wq, const float* __restrict__ Wk,
    const float* __restrict__ Wv, const float* __restrict__ Wo,
    const float* __restrict__ bv, const float* __restrict__ bo,
    f16* __restrict__ Wcat, float* __restrict__ bvo) {
  __shared__ float t0[64][65];
  __shared__ float t1[64 * 64];
  int bid = blockIdx.x, tid = threadIdx.x;
  if (bid < 288) {  // Q,K transposes
    int dt = bid % 12, hh = (bid / 12) % 12, sel = bid / 144;
    const float* W = sel == 0 ? Wq : Wk;
    int d0 = dt * 64;
#pragma unroll
    for (int p = 0; p < 16; ++p) {
      int i = p * 4 + (tid >> 6), kp = tid & 63;
      t0[i][kp] = W[(size_t)(hh * 768 + d0 + i) * 64 + kp];
    }
    __syncthreads();
#pragma unroll
    for (int p = 0; p < 16; ++p) {
      int kp = p * 4 + (tid >> 6), i = tid & 63;
      Wcat[(size_t)(sel * 768 + hh * 64 + kp) * 768 + d0 + i] = (f16)t0[i][kp];
    }
  } else if (bid < 432) {  // V@Wo per (head, d-tile), f32 compute
    int idx = bid - 288, hh = idx / 12, dt = idx % 12, d0 = dt * 64;
#pragma unroll
    for (int p = 0; p < 16; ++p) {
      int i = p * 4 + (tid >> 6), m = tid & 63;
      t0[i][m] = Wv[(size_t)(hh * 768 + d0 + i) * 64 + m];
      t1[i * 64 + m] = Wo[(size_t)(hh * 64 + i) * 64 + m];
    }
    __syncthreads();
    int j = tid & 63;
    for (int p = 0; p < 16; ++p) {
      int i = p * 4 + (tid >> 6);
      float a = 0.f;
      for (int m = 0; m < 64; ++m) a += t0[i][m] * t1[m * 64 + j];
      Wcat[(size_t)(1536 + hh * 64 + j) * 768 + d0 + i] = (f16)a;
    }
  } else {  // bvo
    for (int base = 0; base < 768; base += 256) {
      int idx = base + tid, h2 = idx >> 6, j = idx & 63;
      float a = bo[idx];
      for (int m = 0; m < 64; ++m)
        a += bv[h2 * 64 + m] * Wo[(size_t)(h2 * 64 + m) * 64 + j];
      bvo[idx] = a;
    }
  }
}

__global__ __launch_bounds__(256) void x_to_f16(const float* __restrict__ x,
                                                f16* __restrict__ xh) {
  size_t i = (size_t)blockIdx.x * 256 + threadIdx.x;
  float4 v = reinterpret_cast<const float4*>(x)[i];
  f16x4 o;
  o[0] = (f16)v.x; o[1] = (f16)v.y; o[2] = (f16)v.z; o[3] = (f16)v.w;
  reinterpret_cast<f16x4*>(xh)[i] = o;
}

// ---------------------------------------------------------------------------
// Fused Q/K/Vtilde projection (R9/R13 config) + R14: per-block K-loop
// ROTATION. Co-resident blocks (bid, bid+256, bid+512) start the K-loop at
// offsets {0,6,12} of 24 steps, desynchronizing their barrier phases so one
// block's MFMA covers another's vmcnt drain (the measured ~35% all-stall).
// K-order permutation only changes f32 accumulation order (benign).
// ---------------------------------------------------------------------------
#define QK_AS (128 * 32)  // f16 elems per A buffer (8 KB)
#define QK_BS (192 * 32)  // f16 elems per B buffer (12 KB)
__global__ __launch_bounds__(256, 3) void qkv_gemm(
    const f16* __restrict__ Xh, const f16* __restrict__ Wcat,
    const float* __restrict__ bq, const float* __restrict__ bk,
    f16* __restrict__ Qo, f16* __restrict__ Ko, f16* __restrict__ Vto) {
  __shared__ __align__(16) f16 SH[2 * QK_AS + 2 * QK_BS];  // 40 KB
  int tid = threadIdx.x, lane = tid & 63, wid = tid >> 6;
  int l16 = lane & 15, g4 = lane >> 4;
  int r0 = blockIdx.x * 128, n0 = blockIdx.y * 192;
  int wm = wid & 1, wn = wid >> 1;
  f32x4 acc[4][6] = {};

  const f16* gA[2];
  const f16* gB[3];
  int la[2], lb[3];
#pragma unroll
  for (int ss = 0; ss < 2; ++ss) {
    int s = ss * 256 + tid, row = s >> 2, cs = s & 3;
    int csrc = cs ^ ((row >> 1) & 3);
    gA[ss] = Xh + (size_t)(r0 + row) * 768 + csrc * 8;
    la[ss] = s * 16;
  }
#pragma unroll
  for (int ss = 0; ss < 3; ++ss) {
    int s = ss * 256 + tid, row = s >> 2, cs = s & 3;
    int csrc = cs ^ ((row >> 1) & 3);
    gB[ss] = Wcat + (size_t)(n0 + row) * 768 + csrc * 8;
    lb[ss] = s * 16;
  }
  auto stage = [&](int buf, int kk) {
    char* A = (char*)(SH + buf * QK_AS);
    char* B = (char*)(SH + 2 * QK_AS + buf * QK_BS);
#pragma unroll
    for (int ss = 0; ss < 2; ++ss) gload16(gA[ss] + kk, A + la[ss]);
#pragma unroll
    for (int ss = 0; ss < 3; ++ss) gload16(gB[ss] + kk, B + lb[ss]);
  };
  auto compute = [&](int buf) {
    const f16* A = SH + buf * QK_AS;
    const f16* B = SH + 2 * QK_AS + buf * QK_BS;
    f16x8 af[4], bf[6];
#pragma unroll
    for (int mf = 0; mf < 4; ++mf) {
      int row = wm * 64 + mf * 16 + l16;
      int ch = g4 ^ ((row >> 1) & 3);
      af[mf] = *(const f16x8*)(A + row * 32 + ch * 8);
    }
#pragma unroll
    for (int nf = 0; nf < 6; ++nf) {
      int row = wn * 96 + nf * 16 + l16;
      int ch = g4 ^ ((row >> 1) & 3);
      bf[nf] = *(const f16x8*)(B + row * 32 + ch * 8);
    }
#pragma unroll
    for (int mf = 0; mf < 4; ++mf)
#pragma unroll
      for (int nf = 0; nf < 6; ++nf)
        acc[mf][nf] = __builtin_amdgcn_mfma_f32_16x16x32_f16(af[mf], bf[nf],
                                                             acc[mf][nf], 0, 0, 0);
  };

  // barrier-phase stagger: co-resident blocks differ in (linear bid >> 8)
  int off6 = (((blockIdx.x + 64 * blockIdx.y) >> 8) % 3) * 6;  // 0,6,12
  stage(0, off6 * 32);
  __syncthreads();
  int cur = 0;
  for (int i = 0; i < 24; ++i) {
    bool more = i < 23;
    if (more) {
      int jn = i + 1 + off6;
      if (jn >= 24) jn -= 24;
      stage(cur ^ 1, jn * 32);
    }
    compute(cur);
    if (more) {
      __syncthreads();
      cur ^= 1;
    }
  }

  int sel = n0 / 768;
  int nrem = n0 % 768;
  __syncthreads();
  if (sel < 2) {
    const float* bp = sel == 0 ? bq : bk;
    float scl = sel == 0 ? QSCALE : 1.f;
    f16* dst = sel == 0 ? Qo : Ko;
#pragma unroll
    for (int rh = 0; rh < 2; ++rh) {
      if (wm == rh) {
#pragma unroll
        for (int nf = 0; nf < 6; ++nf) {
          int c = wn * 96 + nf * 16 + l16;
          float bia = bp[nrem + c];
#pragma unroll
          for (int mf = 0; mf < 4; ++mf)
#pragma unroll
            for (int r = 0; r < 4; ++r)
              SH[(mf * 16 + g4 * 4 + r) * 208 + c] =
                  (f16)((acc[mf][nf][r] + bia) * scl);
        }
      }
      __syncthreads();
#pragma unroll
      for (int p = 0; p < 6; ++p) {
        int cl = p * 256 + tid;
        int lr = cl / 24, ch = cl % 24;
        int grow = r0 + rh * 64 + lr;
        int b = grow >> 10, s = grow & 1023;
        int col = nrem + ch * 8;
        int hh = col >> 6, kp = col & 63;
        f16x8 v = *(const f16x8*)(SH + lr * 208 + ch * 8);
        *(f16x8*)(dst + ((size_t)(b * 12 + hh) * 1024 + s) * 64 + kp) = v;
      }
      __syncthreads();
    }
  } else {
#pragma unroll
    for (int rh = 0; rh < 2; ++rh) {
      if (wm == rh) {
#pragma unroll
        for (int nf = 0; nf < 6; ++nf) {
          int c = wn * 96 + nf * 16 + l16;
#pragma unroll
          for (int mf = 0; mf < 4; ++mf)
#pragma unroll
            for (int r = 0; r < 4; ++r)
              SH[c * 72 + mf * 16 + g4 * 4 + r] = (f16)acc[mf][nf][r];
        }
      }
      __syncthreads();
      int grow0 = r0 + rh * 64;
      int b = grow0 >> 10, s0 = grow0 & 1023;
#pragma unroll
      for (int p = 0; p < 6; ++p) {
        int cl = p * 256 + tid;
        int c = cl >> 3, ch = cl & 7;
        int col = nrem + c;
        int hh = col >> 6, kp = col & 63;
        f16x8 v = *(const f16x8*)(SH + c * 72 + ch * 8);
        *(f16x8*)(Vto + ((size_t)(b * 12 + hh) * 64 + kp) * 1024 + s0 + ch * 8) = v;
      }
      __syncthreads();
    }
  }
}

// ---------------------------------------------------------------------------
// Flash attention R14 = R13 + per-block KV-tile ROTATION (same stagger
// mechanism; online softmax is tile-order-invariant — rescale handles any
// max order, sums commute up to f32 rounding, defer-max keeps P <= e^8).
// 4 waves x 32 q-rows, QBLK 128, 768 blocks = 3/CU, T1 remap, glds K/V
// staging, swapped-operand 32x32x16 MFMA, in-reg softmax, Wo folded.
// ---------------------------------------------------------------------------
struct SMemKV { f16 K[2][64 * 64]; f16 V[2][64 * 64]; };
union SMemU { SMemKV kv; float O[4 * 32 * 68]; };

__global__ __launch_bounds__(256, 3) void attn_fused(
    const f16* __restrict__ Qg, const f16* __restrict__ Kg,
    const f16* __restrict__ Vt, const float* __restrict__ bvo,
    f16* __restrict__ XhOut, float* __restrict__ Fout, int last) {
  __shared__ __align__(16) SMemU sm;
  int tid = threadIdx.x, lane = tid & 63, wid = tid >> 6;
  int l32 = lane & 31, hi = lane >> 5;
  int lin = blockIdx.x;
  int qb = lin / 96;       // 0..7
  int hb = lin % 96;       // lin%8 == hb%8 -> XCD owner of this (b,h)
  int hh = hb % 12, bb = hb / 12;
  int q0 = qb * 128;
  size_t bh = (size_t)bb * 12 + hh;
  const f16* Qp = Qg + bh * (1024 * 64);
  const f16* Kp = Kg + bh * (1024 * 64);
  const f16* Vp = Vt + bh * (64 * 1024);

  f16x8 qf[4];
#pragma unroll
  for (int kf = 0; kf < 4; ++kf)
    qf[kf] = *(const f16x8*)(Qp + (size_t)(q0 + wid * 32 + l32) * 64 + kf * 16 + hi * 8);

  // glds staging: slot s = ss*256+tid -> LDS linear s*16B; global source col
  // pre-swizzled (csrc = cs ^ (r&7)) so swizzled reads see original columns.
  const f16* gK[2];
  const f16* gV[2];
  int lofs[2];
#pragma unroll
  for (int ss = 0; ss < 2; ++ss) {
    int s = ss * 256 + tid, r = s >> 3, cs = s & 7;
    int csrc = cs ^ (r & 7);
    gK[ss] = Kp + r * 64 + csrc * 8;             // + t0*64 per tile
    gV[ss] = Vp + (size_t)r * 1024 + csrc * 8;   // + t0 per tile
    lofs[ss] = s * 16;
  }
  auto stage = [&](int buf, int t0) {
    char* K = (char*)sm.kv.K[buf];
    char* V = (char*)sm.kv.V[buf];
#pragma unroll
    for (int ss = 0; ss < 2; ++ss) {
      gload16(gK[ss] + t0 * 64, K + lofs[ss]);
      gload16(gV[ss] + t0, V + lofs[ss]);
    }
  };

  f32x16 oacc0 = {}, oacc1 = {};
  float m = -1e30f, lsum = 0.f;

  // barrier-phase stagger: co-resident blocks get tile-order offsets
  int off = ((lin >> 8) & 3) * 5;  // 0,5,10 of 16 tiles
  stage(0, (off & 15) * 64);
  __syncthreads();  // drains vmcnt -> buf0 ready
  int cur = 0;
  for (int t = 0; t < 16; ++t) {
    bool more = t < 15;
    if (more) stage(cur ^ 1, ((t + 1 + off) & 15) * 64);  // DMA hides under compute
    const f16* Kc = sm.kv.K[cur];
    const f16* Vc = sm.kv.V[cur];
    f32x16 sc0 = {}, sc1 = {};
#pragma unroll
    for (int kf = 0; kf < 4; ++kf) {
      int ch = (2 * kf + hi) ^ (l32 & 7);
      f16x8 k0 = *(const f16x8*)(Kc + l32 * 64 + ch * 8);
      sc0 = __builtin_amdgcn_mfma_f32_32x32x16_f16(k0, qf[kf], sc0, 0, 0, 0);
      f16x8 k1 = *(const f16x8*)(Kc + (32 + l32) * 64 + ch * 8);
      sc1 = __builtin_amdgcn_mfma_f32_32x32x16_f16(k1, qf[kf], sc1, 0, 0, 0);
    }
    float mx[16];
#pragma unroll
    for (int j = 0; j < 16; ++j) mx[j] = fmaxf(sc0[j], sc1[j]);
#pragma unroll
    for (int s = 8; s >= 1; s >>= 1)
#pragma unroll
      for (int j = 0; j < 8; ++j)
        if (j < s) mx[j] = fmaxf(mx[j], mx[j + s]);
    float pmax = fmaxf(mx[0], __shfl_xor(mx[0], 32));
    if (__any(pmax > m + 8.f)) {
      float mn = fmaxf(m, pmax);
      float c = fexp2(m - mn);
      lsum *= c;
#pragma unroll
      for (int j = 0; j < 16; ++j) { oacc0[j] *= c; oacc1[j] *= c; }
      m = mn;
    }
    unsigned w[8][2];
    float qs[8];
#pragma unroll
    for (int qd = 0; qd < 8; ++qd) {
      float a0, a1, a2, a3;
      if (qd < 4) {
        a0 = fexp2(sc0[qd * 4 + 0] - m); a1 = fexp2(sc0[qd * 4 + 1] - m);
        a2 = fexp2(sc0[qd * 4 + 2] - m); a3 = fexp2(sc0[qd * 4 + 3] - m);
      } else {
        a0 = fexp2(sc1[(qd - 4) * 4 + 0] - m); a1 = fexp2(sc1[(qd - 4) * 4 + 1] - m);
        a2 = fexp2(sc1[(qd - 4) * 4 + 2] - m); a3 = fexp2(sc1[(qd - 4) * 4 + 3] - m);
      }
      qs[qd] = (a0 + a1) + (a2 + a3);
      w[qd][0] = __builtin_bit_cast(unsigned, __builtin_amdgcn_cvt_pkrtz(a0, a1));
      w[qd][1] = __builtin_bit_cast(unsigned, __builtin_amdgcn_cvt_pkrtz(a2, a3));
    }
    lsum += ((qs[0] + qs[1]) + (qs[2] + qs[3])) + ((qs[4] + qs[5]) + (qs[6] + qs[7]));
#pragma unroll
    for (int kf = 0; kf < 4; ++kf) {
      int QB = (kf >> 1) * 4 + 2 * (kf & 1);
      unsigned lo0, lo1, hi0, hi1;
      {
        unsigned s0 = hi ? w[QB][0] : w[QB + 1][0];
        unsigned s1 = hi ? w[QB][1] : w[QB + 1][1];
        unsigned r0 = __shfl_xor(s0, 32);
        unsigned r1 = __shfl_xor(s1, 32);
        lo0 = hi ? r0 : w[QB][0];
        lo1 = hi ? r1 : w[QB][1];
        hi0 = hi ? w[QB + 1][0] : r0;
        hi1 = hi ? w[QB + 1][1] : r1;
      }
      u32x4 pw = {lo0, lo1, hi0, hi1};
      f16x8 pf = __builtin_bit_cast(f16x8, pw);
      int ch = (2 * kf + hi) ^ (l32 & 7);
      f16x8 v0 = *(const f16x8*)(Vc + l32 * 64 + ch * 8);
      oacc0 = __builtin_amdgcn_mfma_f32_32x32x16_f16(v0, pf, oacc0, 0, 0, 0);
      f16x8 v1 = *(const f16x8*)(Vc + (32 + l32) * 64 + ch * 8);
      oacc1 = __builtin_amdgcn_mfma_f32_32x32x16_f16(v1, pf, oacc1, 0, 0, 0);
    }
    if (more) {
      __syncthreads();  // drains vmcnt -> next buf landed; readers done
      cur ^= 1;
    }
  }
  float lt = lsum + __shfl_xor(lsum, 32);
  float inv = 1.f / lt;
  __syncthreads();
  float* Ow = sm.O + wid * (32 * 68) + l32 * 68;
#pragma unroll
  for (int dt = 0; dt < 2; ++dt) {
#pragma unroll
    for (int g = 0; g < 4; ++g) {
      int d0 = dt * 32 + g * 8 + hi * 4;
      f32x4 st;
      if (dt == 0) {
        st[0] = oacc0[g * 4 + 0] * inv; st[1] = oacc0[g * 4 + 1] * inv;
        st[2] = oacc0[g * 4 + 2] * inv; st[3] = oacc0[g * 4 + 3] * inv;
      } else {
        st[0] = oacc1[g * 4 + 0] * inv; st[1] = oacc1[g * 4 + 1] * inv;
        st[2] = oacc1[g * 4 + 2] * inv; st[3] = oacc1[g * 4 + 3] * inv;
      }
      *(f32x4*)(Ow + d0) = st;
    }
  }
  __syncthreads();
  int base_q = bb * 1024 + q0;
#pragma unroll
  for (int p = 0; p < 8; ++p) {
    int cl = p * 256 + tid;
    int row = cl >> 4, c = cl & 15;
    f32x4 v = *(const f32x4*)(sm.O + (row >> 5) * (32 * 68) + (row & 31) * 68 + c * 4);
    float4 bv4 = *(const float4*)(bvo + hh * 64 + c * 4);
    v[0] += bv4.x; v[1] += bv4.y; v[2] += bv4.z; v[3] += bv4.w;
    size_t off2 = (size_t)(base_q + row) * 768 + hh * 64 + c * 4;
    if (last) {
      *(f32x4*)(Fout + off2) = v;
    } else {
      f16x4 hq;
      hq[0] = (f16)v[0]; hq[1] = (f16)v[1]; hq[2] = (f16)v[2]; hq[3] = (f16)v[3];
      *(f16x4*)(XhOut + off2) = hq;
    }
  }
}

// ---------------------------------------------------------------------------
extern "C" void kernel_launch(void* const* d_in, const int* in_sizes, int n_in,
                              void* d_out, int out_size, void* d_ws,
                              size_t ws_size, hipStream_t stream) {
  const float* x = (const float*)d_in[0];
  const float* Wq = (const float*)d_in[1];
  const float* bq = (const float*)d_in[2];
  const float* Wk = (const float*)d_in[3];
  const float* bk = (const float*)d_in[4];
  const float* Wv = (const float*)d_in[5];
  const float* bv = (const float*)d_in[6];
  const float* Wo = (const float*)d_in[7];
  const float* bo = (const float*)d_in[8];
  float* out = (float*)d_out;

  char* ws = (char*)d_ws;
  size_t off = 0;
  auto alloc = [&](size_t bytes) -> void* {
    void* p = ws + off;
    off += (bytes + 255) & ~(size_t)255;
    return p;
  };
  f16* Wcat = (f16*)alloc((size_t)NQKV3 * ND * 2);  // 3.54 MB
  float* bvo = (float*)alloc(768 * 4);
  f16* Xh = (f16*)alloc((size_t)NM * ND * 2);   // 12.6 MB
  f16* Qb = (f16*)alloc((size_t)NM * ND * 2);   // B*H*S*HD
  f16* Kb = (f16*)alloc((size_t)NM * ND * 2);
  f16* Vtb = (f16*)alloc((size_t)NM * ND * 2);

  prep_weights<<<433, 256, 0, stream>>>(Wq, Wk, Wv, Wo, bv, bo, Wcat, bvo);
  x_to_f16<<<(NM * ND / 4) / 256, 256, 0, stream>>>(x, Xh);
  for (int l = 0; l < NLAYERS; ++l) {
    qkv_gemm<<<dim3(NM / 128, NQKV3 / 192), 256, 0, stream>>>(
        Xh, Wcat, bq, bk, Qb, Kb, Vtb);
    attn_fused<<<768, 256, 0, stream>>>(
        Qb, Kb, Vtb, bvo, Xh, out, l == NLAYERS - 1);
  }
}

// Round 17
// 918.736 us; speedup vs baseline: 1.0493x; 1.0493x over previous
//
#include <hip/hip_runtime.h>

#define NB 8
#define NS 1024
#define ND 768
#define NH 12
#define NHD 64
#define NLAYERS 12
#define NM (NB * NS)   // 8192 rows
#define NQKV3 (3 * ND) // 2304 output cols of fused QKV GEMM
#define QSCALE 0.1803368802f  // (1/8) * log2(e): softmax runs in exp2 domain

typedef _Float16 f16;
typedef _Float16 f16x8 __attribute__((ext_vector_type(8)));
typedef _Float16 f16x4 __attribute__((ext_vector_type(4)));
typedef _Float16 f16x2 __attribute__((ext_vector_type(2)));
typedef float f32x4 __attribute__((ext_vector_type(4)));
typedef float f32x16 __attribute__((ext_vector_type(16)));
typedef unsigned int u32x4 __attribute__((ext_vector_type(4)));

__device__ inline float fexp2(float x) {
  float r;
  asm("v_exp_f32 %0, %1" : "=v"(r) : "v"(x));
  return r;
}

// async global->LDS DMA, 16B per lane; LDS dest = wave-uniform base + lane*16
__device__ __forceinline__ void gload16(const void* g, void* l) {
  __builtin_amdgcn_global_load_lds(
      (const __attribute__((address_space(1))) void*)g,
      (__attribute__((address_space(3))) void*)l, 16, 0, 0);
}

// ---------------------------------------------------------------------------
// One-time weight prep.
//  Wcat[n][d] (f16, B^T layout), n = sel*768 + h*64 + kp:
//    sel 0: Wq[h][d][kp]   sel 1: Wk[h][d][kp]   sel 2: (Wv@Wo)[h][d][kp]
//  bvo[h*64+j] = sum_m bv[h][m]*Wo[h][m][j] + bo[h][j]
// ---------------------------------------------------------------------------
__global__ __launch_bounds__(256) void prep_weights(
    const float* __restrict__ Wq, const float* __restrict__ Wk,
    const float* __restrict__ Wv, const float* __restrict__ Wo,
    const float* __restrict__ bv, const float* __restrict__ bo,
    f16* __restrict__ Wcat, float* __restrict__ bvo) {
  __shared__ float t0[64][65];
  __shared__ float t1[64 * 64];
  int bid = blockIdx.x, tid = threadIdx.x;
  if (bid < 288) {  // Q,K transposes
    int dt = bid % 12, hh = (bid / 12) % 12, sel = bid / 144;
    const float* W = sel == 0 ? Wq : Wk;
    int d0 = dt * 64;
#pragma unroll
    for (int p = 0; p < 16; ++p) {
      int i = p * 4 + (tid >> 6), kp = tid & 63;
      t0[i][kp] = W[(size_t)(hh * 768 + d0 + i) * 64 + kp];
    }
    __syncthreads();
#pragma unroll
    for (int p = 0; p < 16; ++p) {
      int kp = p * 4 + (tid >> 6), i = tid & 63;
      Wcat[(size_t)(sel * 768 + hh * 64 + kp) * 768 + d0 + i] = (f16)t0[i][kp];
    }
  } else if (bid < 432) {  // V@Wo per (head, d-tile), f32 compute
    int idx = bid - 288, hh = idx / 12, dt = idx % 12, d0 = dt * 64;
#pragma unroll
    for (int p = 0; p < 16; ++p) {
      int i = p * 4 + (tid >> 6), m = tid & 63;
      t0[i][m] = Wv[(size_t)(hh * 768 + d0 + i) * 64 + m];
      t1[i * 64 + m] = Wo[(size_t)(hh * 64 + i) * 64 + m];
    }
    __syncthreads();
    int j = tid & 63;
    for (int p = 0; p < 16; ++p) {
      int i = p * 4 + (tid >> 6);
      float a = 0.f;
      for (int m = 0; m < 64; ++m) a += t0[i][m] * t1[m * 64 + j];
      Wcat[(size_t)(1536 + hh * 64 + j) * 768 + d0 + i] = (f16)a;
    }
  } else {  // bvo
    for (int base = 0; base < 768; base += 256) {
      int idx = base + tid, h2 = idx >> 6, j = idx & 63;
      float a = bo[idx];
      for (int m = 0; m < 64; ++m)
        a += bv[h2 * 64 + m] * Wo[(size_t)(h2 * 64 + m) * 64 + j];
      bvo[idx] = a;
    }
  }
}

__global__ __launch_bounds__(256) void x_to_f16(const float* __restrict__ x,
                                                f16* __restrict__ xh) {
  size_t i = (size_t)blockIdx.x * 256 + threadIdx.x;
  float4 v = reinterpret_cast<const float4*>(x)[i];
  f16x4 o;
  o[0] = (f16)v.x; o[1] = (f16)v.y; o[2] = (f16)v.z; o[3] = (f16)v.w;
  reinterpret_cast<f16x4*>(xh)[i] = o;
}

// ---------------------------------------------------------------------------
// Fused Q/K/Vtilde projection (R9 config): 128x192 tile, 4 waves,
// glds width=16 staging with pre-swizzled global source, 768 blocks = 3/CU,
// LDS-transpose epilogues with coalesced f16x8 stores.
// ---------------------------------------------------------------------------
#define QK_AS (128 * 32)  // f16 elems per A buffer (8 KB)
#define QK_BS (192 * 32)  // f16 elems per B buffer (12 KB)
__global__ __launch_bounds__(256, 3) void qkv_gemm(
    const f16* __restrict__ Xh, const f16* __restrict__ Wcat,
    const float* __restrict__ bq, const float* __restrict__ bk,
    f16* __restrict__ Qo, f16* __restrict__ Ko, f16* __restrict__ Vto) {
  __shared__ __align__(16) f16 SH[2 * QK_AS + 2 * QK_BS];  // 40 KB
  int tid = threadIdx.x, lane = tid & 63, wid = tid >> 6;
  int l16 = lane & 15, g4 = lane >> 4;
  int r0 = blockIdx.x * 128, n0 = blockIdx.y * 192;
  int wm = wid & 1, wn = wid >> 1;
  f32x4 acc[4][6] = {};

  const f16* gA[2];
  const f16* gB[3];
  int la[2], lb[3];
#pragma unroll
  for (int ss = 0; ss < 2; ++ss) {
    int s = ss * 256 + tid, row = s >> 2, cs = s & 3;
    int csrc = cs ^ ((row >> 1) & 3);
    gA[ss] = Xh + (size_t)(r0 + row) * 768 + csrc * 8;
    la[ss] = s * 16;
  }
#pragma unroll
  for (int ss = 0; ss < 3; ++ss) {
    int s = ss * 256 + tid, row = s >> 2, cs = s & 3;
    int csrc = cs ^ ((row >> 1) & 3);
    gB[ss] = Wcat + (size_t)(n0 + row) * 768 + csrc * 8;
    lb[ss] = s * 16;
  }
  auto stage = [&](int buf, int kk) {
    char* A = (char*)(SH + buf * QK_AS);
    char* B = (char*)(SH + 2 * QK_AS + buf * QK_BS);
#pragma unroll
    for (int ss = 0; ss < 2; ++ss) gload16(gA[ss] + kk, A + la[ss]);
#pragma unroll
    for (int ss = 0; ss < 3; ++ss) gload16(gB[ss] + kk, B + lb[ss]);
  };
  auto compute = [&](int buf) {
    const f16* A = SH + buf * QK_AS;
    const f16* B = SH + 2 * QK_AS + buf * QK_BS;
    f16x8 af[4], bf[6];
#pragma unroll
    for (int mf = 0; mf < 4; ++mf) {
      int row = wm * 64 + mf * 16 + l16;
      int ch = g4 ^ ((row >> 1) & 3);
      af[mf] = *(const f16x8*)(A + row * 32 + ch * 8);
    }
#pragma unroll
    for (int nf = 0; nf < 6; ++nf) {
      int row = wn * 96 + nf * 16 + l16;
      int ch = g4 ^ ((row >> 1) & 3);
      bf[nf] = *(const f16x8*)(B + row * 32 + ch * 8);
    }
#pragma unroll
    for (int mf = 0; mf < 4; ++mf)
#pragma unroll
      for (int nf = 0; nf < 6; ++nf)
        acc[mf][nf] = __builtin_amdgcn_mfma_f32_16x16x32_f16(af[mf], bf[nf],
                                                             acc[mf][nf], 0, 0, 0);
  };

  stage(0, 0);
  __syncthreads();
  int cur = 0;
  for (int kk = 0; kk < 768; kk += 32) {
    bool more = kk + 32 < 768;
    if (more) stage(cur ^ 1, kk + 32);
    compute(cur);
    if (more) {
      __syncthreads();
      cur ^= 1;
    }
  }

  int sel = n0 / 768;
  int nrem = n0 % 768;
  __syncthreads();
  if (sel < 2) {
    const float* bp = sel == 0 ? bq : bk;
    float scl = sel == 0 ? QSCALE : 1.f;
    f16* dst = sel == 0 ? Qo : Ko;
#pragma unroll
    for (int rh = 0; rh < 2; ++rh) {
      if (wm == rh) {
#pragma unroll
        for (int nf = 0; nf < 6; ++nf) {
          int c = wn * 96 + nf * 16 + l16;
          float bia = bp[nrem + c];
#pragma unroll
          for (int mf = 0; mf < 4; ++mf)
#pragma unroll
            for (int r = 0; r < 4; ++r)
              SH[(mf * 16 + g4 * 4 + r) * 208 + c] =
                  (f16)((acc[mf][nf][r] + bia) * scl);
        }
      }
      __syncthreads();
#pragma unroll
      for (int p = 0; p < 6; ++p) {
        int cl = p * 256 + tid;
        int lr = cl / 24, ch = cl % 24;
        int grow = r0 + rh * 64 + lr;
        int b = grow >> 10, s = grow & 1023;
        int col = nrem + ch * 8;
        int hh = col >> 6, kp = col & 63;
        f16x8 v = *(const f16x8*)(SH + lr * 208 + ch * 8);
        *(f16x8*)(dst + ((size_t)(b * 12 + hh) * 1024 + s) * 64 + kp) = v;
      }
      __syncthreads();
    }
  } else {
#pragma unroll
    for (int rh = 0; rh < 2; ++rh) {
      if (wm == rh) {
#pragma unroll
        for (int nf = 0; nf < 6; ++nf) {
          int c = wn * 96 + nf * 16 + l16;
#pragma unroll
          for (int mf = 0; mf < 4; ++mf)
#pragma unroll
            for (int r = 0; r < 4; ++r)
              SH[c * 72 + mf * 16 + g4 * 4 + r] = (f16)acc[mf][nf][r];
        }
      }
      __syncthreads();
      int grow0 = r0 + rh * 64;
      int b = grow0 >> 10, s0 = grow0 & 1023;
#pragma unroll
      for (int p = 0; p < 6; ++p) {
        int cl = p * 256 + tid;
        int c = cl >> 3, ch = cl & 7;
        int col = nrem + c;
        int hh = col >> 6, kp = col & 63;
        f16x8 v = *(const f16x8*)(SH + c * 72 + ch * 8);
        *(f16x8*)(Vto + ((size_t)(b * 12 + hh) * 64 + kp) * 1024 + s0 + ch * 8) = v;
      }
      __syncthreads();
    }
  }
}

// ---------------------------------------------------------------------------
// Flash attention (R13 = session best): 4 waves x 32 q-rows, QBLK 128,
// 768 blocks = 3/CU exact, T1 remap lin%8==hb%8 (K/V L2-resident per XCD),
// K/V staged via global_load_lds (pre-swizzled source, linear LDS dest),
// swapped-operand 32x32x16 MFMA, in-reg softmax (shfl exchange), defer-max,
// Wo folded into Vtilde. In-order tile sweep (R14 rotation broke L2 reuse).
// ---------------------------------------------------------------------------
struct SMemKV { f16 K[2][64 * 64]; f16 V[2][64 * 64]; };
union SMemU { SMemKV kv; float O[4 * 32 * 68]; };

__global__ __launch_bounds__(256, 3) void attn_fused(
    const f16* __restrict__ Qg, const f16* __restrict__ Kg,
    const f16* __restrict__ Vt, const float* __restrict__ bvo,
    f16* __restrict__ XhOut, float* __restrict__ Fout, int last) {
  __shared__ __align__(16) SMemU sm;
  int tid = threadIdx.x, lane = tid & 63, wid = tid >> 6;
  int l32 = lane & 31, hi = lane >> 5;
  int lin = blockIdx.x;
  int qb = lin / 96;       // 0..7
  int hb = lin % 96;       // lin%8 == hb%8 -> XCD owner of this (b,h)
  int hh = hb % 12, bb = hb / 12;
  int q0 = qb * 128;
  size_t bh = (size_t)bb * 12 + hh;
  const f16* Qp = Qg + bh * (1024 * 64);
  const f16* Kp = Kg + bh * (1024 * 64);
  const f16* Vp = Vt + bh * (64 * 1024);

  f16x8 qf[4];
#pragma unroll
  for (int kf = 0; kf < 4; ++kf)
    qf[kf] = *(const f16x8*)(Qp + (size_t)(q0 + wid * 32 + l32) * 64 + kf * 16 + hi * 8);

  // glds staging: slot s = ss*256+tid -> LDS linear s*16B; global source col
  // pre-swizzled (csrc = cs ^ (r&7)) so swizzled reads see original columns.
  const f16* gK[2];
  const f16* gV[2];
  int lofs[2];
#pragma unroll
  for (int ss = 0; ss < 2; ++ss) {
    int s = ss * 256 + tid, r = s >> 3, cs = s & 7;
    int csrc = cs ^ (r & 7);
    gK[ss] = Kp + r * 64 + csrc * 8;             // + t0*64 per tile
    gV[ss] = Vp + (size_t)r * 1024 + csrc * 8;   // + t0 per tile
    lofs[ss] = s * 16;
  }
  auto stage = [&](int buf, int t0) {
    char* K = (char*)sm.kv.K[buf];
    char* V = (char*)sm.kv.V[buf];
#pragma unroll
    for (int ss = 0; ss < 2; ++ss) {
      gload16(gK[ss] + t0 * 64, K + lofs[ss]);
      gload16(gV[ss] + t0, V + lofs[ss]);
    }
  };

  f32x16 oacc0 = {}, oacc1 = {};
  float m = -1e30f, lsum = 0.f;

  stage(0, 0);
  __syncthreads();  // drains vmcnt -> buf0 ready
  int cur = 0;
  for (int t = 0; t < 16; ++t) {
    bool more = t < 15;
    if (more) stage(cur ^ 1, (t + 1) * 64);  // DMA hides under tile compute
    const f16* Kc = sm.kv.K[cur];
    const f16* Vc = sm.kv.V[cur];
    f32x16 sc0 = {}, sc1 = {};
#pragma unroll
    for (int kf = 0; kf < 4; ++kf) {
      int ch = (2 * kf + hi) ^ (l32 & 7);
      f16x8 k0 = *(const f16x8*)(Kc + l32 * 64 + ch * 8);
      sc0 = __builtin_amdgcn_mfma_f32_32x32x16_f16(k0, qf[kf], sc0, 0, 0, 0);
      f16x8 k1 = *(const f16x8*)(Kc + (32 + l32) * 64 + ch * 8);
      sc1 = __builtin_amdgcn_mfma_f32_32x32x16_f16(k1, qf[kf], sc1, 0, 0, 0);
    }
    float mx[16];
#pragma unroll
    for (int j = 0; j < 16; ++j) mx[j] = fmaxf(sc0[j], sc1[j]);
#pragma unroll
    for (int s = 8; s >= 1; s >>= 1)
#pragma unroll
      for (int j = 0; j < 8; ++j)
        if (j < s) mx[j] = fmaxf(mx[j], mx[j + s]);
    float pmax = fmaxf(mx[0], __shfl_xor(mx[0], 32));
    if (__any(pmax > m + 8.f)) {
      float mn = fmaxf(m, pmax);
      float c = fexp2(m - mn);
      lsum *= c;
#pragma unroll
      for (int j = 0; j < 16; ++j) { oacc0[j] *= c; oacc1[j] *= c; }
      m = mn;
    }
    unsigned w[8][2];
    float qs[8];
#pragma unroll
    for (int qd = 0; qd < 8; ++qd) {
      float a0, a1, a2, a3;
      if (qd < 4) {
        a0 = fexp2(sc0[qd * 4 + 0] - m); a1 = fexp2(sc0[qd * 4 + 1] - m);
        a2 = fexp2(sc0[qd * 4 + 2] - m); a3 = fexp2(sc0[qd * 4 + 3] - m);
      } else {
        a0 = fexp2(sc1[(qd - 4) * 4 + 0] - m); a1 = fexp2(sc1[(qd - 4) * 4 + 1] - m);
        a2 = fexp2(sc1[(qd - 4) * 4 + 2] - m); a3 = fexp2(sc1[(qd - 4) * 4 + 3] - m);
      }
      qs[qd] = (a0 + a1) + (a2 + a3);
      w[qd][0] = __builtin_bit_cast(unsigned, __builtin_amdgcn_cvt_pkrtz(a0, a1));
      w[qd][1] = __builtin_bit_cast(unsigned, __builtin_amdgcn_cvt_pkrtz(a2, a3));
    }
    lsum += ((qs[0] + qs[1]) + (qs[2] + qs[3])) + ((qs[4] + qs[5]) + (qs[6] + qs[7]));
#pragma unroll
    for (int kf = 0; kf < 4; ++kf) {
      int QB = (kf >> 1) * 4 + 2 * (kf & 1);
      unsigned lo0, lo1, hi0, hi1;
      {
        unsigned s0 = hi ? w[QB][0] : w[QB + 1][0];
        unsigned s1 = hi ? w[QB][1] : w[QB + 1][1];
        unsigned r0 = __shfl_xor(s0, 32);
        unsigned r1 = __shfl_xor(s1, 32);
        lo0 = hi ? r0 : w[QB][0];
        lo1 = hi ? r1 : w[QB][1];
        hi0 = hi ? w[QB + 1][0] : r0;
        hi1 = hi ? w[QB + 1][1] : r1;
      }
      u32x4 pw = {lo0, lo1, hi0, hi1};
      f16x8 pf = __builtin_bit_cast(f16x8, pw);
      int ch = (2 * kf + hi) ^ (l32 & 7);
      f16x8 v0 = *(const f16x8*)(Vc + l32 * 64 + ch * 8);
      oacc0 = __builtin_amdgcn_mfma_f32_32x32x16_f16(v0, pf, oacc0, 0, 0, 0);
      f16x8 v1 = *(const f16x8*)(Vc + (32 + l32) * 64 + ch * 8);
      oacc1 = __builtin_amdgcn_mfma_f32_32x32x16_f16(v1, pf, oacc1, 0, 0, 0);
    }
    if (more) {
      __syncthreads();  // drains vmcnt -> next buf landed; readers done
      cur ^= 1;
    }
  }
  float lt = lsum + __shfl_xor(lsum, 32);
  float inv = 1.f / lt;
  __syncthreads();
  float* Ow = sm.O + wid * (32 * 68) + l32 * 68;
#pragma unroll
  for (int dt = 0; dt < 2; ++dt) {
#pragma unroll
    for (int g = 0; g < 4; ++g) {
      int d0 = dt * 32 + g * 8 + hi * 4;
      f32x4 st;
      if (dt == 0) {
        st[0] = oacc0[g * 4 + 0] * inv; st[1] = oacc0[g * 4 + 1] * inv;
        st[2] = oacc0[g * 4 + 2] * inv; st[3] = oacc0[g * 4 + 3] * inv;
      } else {
        st[0] = oacc1[g * 4 + 0] * inv; st[1] = oacc1[g * 4 + 1] * inv;
        st[2] = oacc1[g * 4 + 2] * inv; st[3] = oacc1[g * 4 + 3] * inv;
      }
      *(f32x4*)(Ow + d0) = st;
    }
  }
  __syncthreads();
  int base_q = bb * 1024 + q0;
#pragma unroll
  for (int p = 0; p < 8; ++p) {
    int cl = p * 256 + tid;
    int row = cl >> 4, c = cl & 15;
    f32x4 v = *(const f32x4*)(sm.O + (row >> 5) * (32 * 68) + (row & 31) * 68 + c * 4);
    float4 bv4 = *(const float4*)(bvo + hh * 64 + c * 4);
    v[0] += bv4.x; v[1] += bv4.y; v[2] += bv4.z; v[3] += bv4.w;
    size_t off = (size_t)(base_q + row) * 768 + hh * 64 + c * 4;
    if (last) {
      *(f32x4*)(Fout + off) = v;
    } else {
      f16x4 hq;
      hq[0] = (f16)v[0]; hq[1] = (f16)v[1]; hq[2] = (f16)v[2]; hq[3] = (f16)v[3];
      *(f16x4*)(XhOut + off) = hq;
    }
  }
}

// ---------------------------------------------------------------------------
extern "C" void kernel_launch(void* const* d_in, const int* in_sizes, int n_in,
                              void* d_out, int out_size, void* d_ws,
                              size_t ws_size, hipStream_t stream) {
  const float* x = (const float*)d_in[0];
  const float* Wq = (const float*)d_in[1];
  const float* bq = (const float*)d_in[2];
  const float* Wk = (const float*)d_in[3];
  const float* bk = (const float*)d_in[4];
  const float* Wv = (const float*)d_in[5];
  const float* bv = (const float*)d_in[6];
  const float* Wo = (const float*)d_in[7];
  const float* bo = (const float*)d_in[8];
  float* out = (float*)d_out;

  char* ws = (char*)d_ws;
  size_t off = 0;
  auto alloc = [&](size_t bytes) -> void* {
    void* p = ws + off;
    off += (bytes + 255) & ~(size_t)255;
    return p;
  };
  f16* Wcat = (f16*)alloc((size_t)NQKV3 * ND * 2);  // 3.54 MB
  float* bvo = (float*)alloc(768 * 4);
  f16* Xh = (f16*)alloc((size_t)NM * ND * 2);   // 12.6 MB
  f16* Qb = (f16*)alloc((size_t)NM * ND * 2);   // B*H*S*HD
  f16* Kb = (f16*)alloc((size_t)NM * ND * 2);
  f16* Vtb = (f16*)alloc((size_t)NM * ND * 2);

  prep_weights<<<433, 256, 0, stream>>>(Wq, Wk, Wv, Wo, bv, bo, Wcat, bvo);
  x_to_f16<<<(NM * ND / 4) / 256, 256, 0, stream>>>(x, Xh);
  for (int l = 0; l < NLAYERS; ++l) {
    qkv_gemm<<<dim3(NM / 128, NQKV3 / 192), 256, 0, stream>>>(
        Xh, Wcat, bq, bk, Qb, Kb, Vtb);
    attn_fused<<<768, 256, 0, stream>>>(
        Qb, Kb, Vtb, bvo, Xh, out, l == NLAYERS - 1);
  }
}

// Round 18
// 916.017 us; speedup vs baseline: 1.0524x; 1.0030x over previous
//
#include <hip/hip_runtime.h>

#define NB 8
#define NS 1024
#define ND 768
#define NH 12
#define NHD 64
#define NLAYERS 12
#define NM (NB * NS)   // 8192 rows
#define NQKV3 (3 * ND) // 2304 output cols of fused QKV GEMM
#define QSCALE 0.1803368802f  // (1/8) * log2(e): softmax runs in exp2 domain

typedef _Float16 f16;
typedef _Float16 f16x8 __attribute__((ext_vector_type(8)));
typedef _Float16 f16x4 __attribute__((ext_vector_type(4)));
typedef _Float16 f16x2 __attribute__((ext_vector_type(2)));
typedef float f32x4 __attribute__((ext_vector_type(4)));
typedef float f32x16 __attribute__((ext_vector_type(16)));
typedef unsigned int u32x4 __attribute__((ext_vector_type(4)));

__device__ inline float fexp2(float x) {
  float r;
  asm("v_exp_f32 %0, %1" : "=v"(r) : "v"(x));
  return r;
}

// Lane-half exchange via v_permlane32_swap_b32 THROUGH THE BUILTIN (compiler
// inserts the required VALU->permlane wait states; the R10 inline-asm version
// hit the unhandled hazard and produced sporadic 1e-2 errors).
// Semantics: new_a = {a.lo32, b.lo32}, new_b = {a.hi32, b.hi32}.
#if defined(__has_builtin)
#if __has_builtin(__builtin_amdgcn_permlane32_swap)
#define HAVE_PLSWAP 1
#endif
#endif
#ifdef HAVE_PLSWAP
typedef unsigned u32x2 __attribute__((ext_vector_type(2)));
__device__ __forceinline__ void plswap(unsigned &a, unsigned &b) {
  u32x2 r = __builtin_amdgcn_permlane32_swap(a, b, false, false);
  a = r[0];
  b = r[1];
}
__device__ __forceinline__ void plswapf(float &a, float &b) {
  unsigned ua = __builtin_bit_cast(unsigned, a);
  unsigned ub = __builtin_bit_cast(unsigned, b);
  plswap(ua, ub);
  a = __builtin_bit_cast(float, ua);
  b = __builtin_bit_cast(float, ub);
}
#endif

// async global->LDS DMA, 16B per lane; LDS dest = wave-uniform base + lane*16
__device__ __forceinline__ void gload16(const void* g, void* l) {
  __builtin_amdgcn_global_load_lds(
      (const __attribute__((address_space(1))) void*)g,
      (__attribute__((address_space(3))) void*)l, 16, 0, 0);
}

// ---------------------------------------------------------------------------
// One-time weight prep.
//  Wcat[n][d] (f16, B^T layout), n = sel*768 + h*64 + kp:
//    sel 0: Wq[h][d][kp]   sel 1: Wk[h][d][kp]   sel 2: (Wv@Wo)[h][d][kp]
//  bvo[h*64+j] = sum_m bv[h][m]*Wo[h][m][j] + bo[h][j]
// ---------------------------------------------------------------------------
__global__ __launch_bounds__(256) void prep_weights(
    const float* __restrict__ Wq, const float* __restrict__ Wk,
    const float* __restrict__ Wv, const float* __restrict__ Wo,
    const float* __restrict__ bv, const float* __restrict__ bo,
    f16* __restrict__ Wcat, float* __restrict__ bvo) {
  __shared__ float t0[64][65];
  __shared__ float t1[64 * 64];
  int bid = blockIdx.x, tid = threadIdx.x;
  if (bid < 288) {  // Q,K transposes
    int dt = bid % 12, hh = (bid / 12) % 12, sel = bid / 144;
    const float* W = sel == 0 ? Wq : Wk;
    int d0 = dt * 64;
#pragma unroll
    for (int p = 0; p < 16; ++p) {
      int i = p * 4 + (tid >> 6), kp = tid & 63;
      t0[i][kp] = W[(size_t)(hh * 768 + d0 + i) * 64 + kp];
    }
    __syncthreads();
#pragma unroll
    for (int p = 0; p < 16; ++p) {
      int kp = p * 4 + (tid >> 6), i = tid & 63;
      Wcat[(size_t)(sel * 768 + hh * 64 + kp) * 768 + d0 + i] = (f16)t0[i][kp];
    }
  } else if (bid < 432) {  // V@Wo per (head, d-tile), f32 compute
    int idx = bid - 288, hh = idx / 12, dt = idx % 12, d0 = dt * 64;
#pragma unroll
    for (int p = 0; p < 16; ++p) {
      int i = p * 4 + (tid >> 6), m = tid & 63;
      t0[i][m] = Wv[(size_t)(hh * 768 + d0 + i) * 64 + m];
      t1[i * 64 + m] = Wo[(size_t)(hh * 64 + i) * 64 + m];
    }
    __syncthreads();
    int j = tid & 63;
    for (int p = 0; p < 16; ++p) {
      int i = p * 4 + (tid >> 6);
      float a = 0.f;
      for (int m = 0; m < 64; ++m) a += t0[i][m] * t1[m * 64 + j];
      Wcat[(size_t)(1536 + hh * 64 + j) * 768 + d0 + i] = (f16)a;
    }
  } else {  // bvo
    for (int base = 0; base < 768; base += 256) {
      int idx = base + tid, h2 = idx >> 6, j = idx & 63;
      float a = bo[idx];
      for (int m = 0; m < 64; ++m)
        a += bv[h2 * 64 + m] * Wo[(size_t)(h2 * 64 + m) * 64 + j];
      bvo[idx] = a;
    }
  }
}

__global__ __launch_bounds__(256) void x_to_f16(const float* __restrict__ x,
                                                f16* __restrict__ xh) {
  size_t i = (size_t)blockIdx.x * 256 + threadIdx.x;
  float4 v = reinterpret_cast<const float4*>(x)[i];
  f16x4 o;
  o[0] = (f16)v.x; o[1] = (f16)v.y; o[2] = (f16)v.z; o[3] = (f16)v.w;
  reinterpret_cast<f16x4*>(xh)[i] = o;
}

// ---------------------------------------------------------------------------
// Fused Q/K/Vtilde projection (R9 config): 128x192 tile, 4 waves,
// glds width=16 staging with pre-swizzled global source, 768 blocks = 3/CU,
// LDS-transpose epilogues with coalesced f16x8 stores.
// ---------------------------------------------------------------------------
#define QK_AS (128 * 32)  // f16 elems per A buffer (8 KB)
#define QK_BS (192 * 32)  // f16 elems per B buffer (12 KB)
__global__ __launch_bounds__(256, 3) void qkv_gemm(
    const f16* __restrict__ Xh, const f16* __restrict__ Wcat,
    const float* __restrict__ bq, const float* __restrict__ bk,
    f16* __restrict__ Qo, f16* __restrict__ Ko, f16* __restrict__ Vto) {
  __shared__ __align__(16) f16 SH[2 * QK_AS + 2 * QK_BS];  // 40 KB
  int tid = threadIdx.x, lane = tid & 63, wid = tid >> 6;
  int l16 = lane & 15, g4 = lane >> 4;
  int r0 = blockIdx.x * 128, n0 = blockIdx.y * 192;
  int wm = wid & 1, wn = wid >> 1;
  f32x4 acc[4][6] = {};

  const f16* gA[2];
  const f16* gB[3];
  int la[2], lb[3];
#pragma unroll
  for (int ss = 0; ss < 2; ++ss) {
    int s = ss * 256 + tid, row = s >> 2, cs = s & 3;
    int csrc = cs ^ ((row >> 1) & 3);
    gA[ss] = Xh + (size_t)(r0 + row) * 768 + csrc * 8;
    la[ss] = s * 16;
  }
#pragma unroll
  for (int ss = 0; ss < 3; ++ss) {
    int s = ss * 256 + tid, row = s >> 2, cs = s & 3;
    int csrc = cs ^ ((row >> 1) & 3);
    gB[ss] = Wcat + (size_t)(n0 + row) * 768 + csrc * 8;
    lb[ss] = s * 16;
  }
  auto stage = [&](int buf, int kk) {
    char* A = (char*)(SH + buf * QK_AS);
    char* B = (char*)(SH + 2 * QK_AS + buf * QK_BS);
#pragma unroll
    for (int ss = 0; ss < 2; ++ss) gload16(gA[ss] + kk, A + la[ss]);
#pragma unroll
    for (int ss = 0; ss < 3; ++ss) gload16(gB[ss] + kk, B + lb[ss]);
  };
  auto compute = [&](int buf) {
    const f16* A = SH + buf * QK_AS;
    const f16* B = SH + 2 * QK_AS + buf * QK_BS;
    f16x8 af[4], bf[6];
#pragma unroll
    for (int mf = 0; mf < 4; ++mf) {
      int row = wm * 64 + mf * 16 + l16;
      int ch = g4 ^ ((row >> 1) & 3);
      af[mf] = *(const f16x8*)(A + row * 32 + ch * 8);
    }
#pragma unroll
    for (int nf = 0; nf < 6; ++nf) {
      int row = wn * 96 + nf * 16 + l16;
      int ch = g4 ^ ((row >> 1) & 3);
      bf[nf] = *(const f16x8*)(B + row * 32 + ch * 8);
    }
#pragma unroll
    for (int mf = 0; mf < 4; ++mf)
#pragma unroll
      for (int nf = 0; nf < 6; ++nf)
        acc[mf][nf] = __builtin_amdgcn_mfma_f32_16x16x32_f16(af[mf], bf[nf],
                                                             acc[mf][nf], 0, 0, 0);
  };

  stage(0, 0);
  __syncthreads();
  int cur = 0;
  for (int kk = 0; kk < 768; kk += 32) {
    bool more = kk + 32 < 768;
    if (more) stage(cur ^ 1, kk + 32);
    compute(cur);
    if (more) {
      __syncthreads();
      cur ^= 1;
    }
  }

  int sel = n0 / 768;
  int nrem = n0 % 768;
  __syncthreads();
  if (sel < 2) {
    const float* bp = sel == 0 ? bq : bk;
    float scl = sel == 0 ? QSCALE : 1.f;
    f16* dst = sel == 0 ? Qo : Ko;
#pragma unroll
    for (int rh = 0; rh < 2; ++rh) {
      if (wm == rh) {
#pragma unroll
        for (int nf = 0; nf < 6; ++nf) {
          int c = wn * 96 + nf * 16 + l16;
          float bia = bp[nrem + c];
#pragma unroll
          for (int mf = 0; mf < 4; ++mf)
#pragma unroll
            for (int r = 0; r < 4; ++r)
              SH[(mf * 16 + g4 * 4 + r) * 208 + c] =
                  (f16)((acc[mf][nf][r] + bia) * scl);
        }
      }
      __syncthreads();
#pragma unroll
      for (int p = 0; p < 6; ++p) {
        int cl = p * 256 + tid;
        int lr = cl / 24, ch = cl % 24;
        int grow = r0 + rh * 64 + lr;
        int b = grow >> 10, s = grow & 1023;
        int col = nrem + ch * 8;
        int hh = col >> 6, kp = col & 63;
        f16x8 v = *(const f16x8*)(SH + lr * 208 + ch * 8);
        *(f16x8*)(dst + ((size_t)(b * 12 + hh) * 1024 + s) * 64 + kp) = v;
      }
      __syncthreads();
    }
  } else {
#pragma unroll
    for (int rh = 0; rh < 2; ++rh) {
      if (wm == rh) {
#pragma unroll
        for (int nf = 0; nf < 6; ++nf) {
          int c = wn * 96 + nf * 16 + l16;
#pragma unroll
          for (int mf = 0; mf < 4; ++mf)
#pragma unroll
            for (int r = 0; r < 4; ++r)
              SH[c * 72 + mf * 16 + g4 * 4 + r] = (f16)acc[mf][nf][r];
        }
      }
      __syncthreads();
      int grow0 = r0 + rh * 64;
      int b = grow0 >> 10, s0 = grow0 & 1023;
#pragma unroll
      for (int p = 0; p < 6; ++p) {
        int cl = p * 256 + tid;
        int c = cl >> 3, ch = cl & 7;
        int col = nrem + c;
        int hh = col >> 6, kp = col & 63;
        f16x8 v = *(const f16x8*)(SH + c * 72 + ch * 8);
        *(f16x8*)(Vto + ((size_t)(b * 12 + hh) * 64 + kp) * 1024 + s0 + ch * 8) = v;
      }
      __syncthreads();
    }
  }
}

// ---------------------------------------------------------------------------
// Flash attention (R13 structure): 4 waves x 32 q-rows, QBLK 128, 768 blocks
// = 3/CU exact, T1 remap lin%8==hb%8, glds K/V staging, swapped-operand
// 32x32x16 MFMA, in-reg softmax, defer-max, Wo folded into Vtilde.
// R17: ALL xor-32 exchanges via __builtin_amdgcn_permlane32_swap (builtin =>
// compiler-inserted hazard waits; replaces ds_bpermute shuffles + cndmask
// picks). Falls back to the R16 shfl path if the builtin is unavailable.
// ---------------------------------------------------------------------------
struct SMemKV { f16 K[2][64 * 64]; f16 V[2][64 * 64]; };
union SMemU { SMemKV kv; float O[4 * 32 * 68]; };

__global__ __launch_bounds__(256, 3) void attn_fused(
    const f16* __restrict__ Qg, const f16* __restrict__ Kg,
    const f16* __restrict__ Vt, const float* __restrict__ bvo,
    f16* __restrict__ XhOut, float* __restrict__ Fout, int last) {
  __shared__ __align__(16) SMemU sm;
  int tid = threadIdx.x, lane = tid & 63, wid = tid >> 6;
  int l32 = lane & 31, hi = lane >> 5;
  int lin = blockIdx.x;
  int qb = lin / 96;       // 0..7
  int hb = lin % 96;       // lin%8 == hb%8 -> XCD owner of this (b,h)
  int hh = hb % 12, bb = hb / 12;
  int q0 = qb * 128;
  size_t bh = (size_t)bb * 12 + hh;
  const f16* Qp = Qg + bh * (1024 * 64);
  const f16* Kp = Kg + bh * (1024 * 64);
  const f16* Vp = Vt + bh * (64 * 1024);

  f16x8 qf[4];
#pragma unroll
  for (int kf = 0; kf < 4; ++kf)
    qf[kf] = *(const f16x8*)(Qp + (size_t)(q0 + wid * 32 + l32) * 64 + kf * 16 + hi * 8);

  // glds staging: slot s = ss*256+tid -> LDS linear s*16B; global source col
  // pre-swizzled (csrc = cs ^ (r&7)) so swizzled reads see original columns.
  const f16* gK[2];
  const f16* gV[2];
  int lofs[2];
#pragma unroll
  for (int ss = 0; ss < 2; ++ss) {
    int s = ss * 256 + tid, r = s >> 3, cs = s & 7;
    int csrc = cs ^ (r & 7);
    gK[ss] = Kp + r * 64 + csrc * 8;             // + t0*64 per tile
    gV[ss] = Vp + (size_t)r * 1024 + csrc * 8;   // + t0 per tile
    lofs[ss] = s * 16;
  }
  auto stage = [&](int buf, int t0) {
    char* K = (char*)sm.kv.K[buf];
    char* V = (char*)sm.kv.V[buf];
#pragma unroll
    for (int ss = 0; ss < 2; ++ss) {
      gload16(gK[ss] + t0 * 64, K + lofs[ss]);
      gload16(gV[ss] + t0, V + lofs[ss]);
    }
  };

  f32x16 oacc0 = {}, oacc1 = {};
  float m = -1e30f, lsum = 0.f;

  stage(0, 0);
  __syncthreads();  // drains vmcnt -> buf0 ready
  int cur = 0;
  for (int t = 0; t < 16; ++t) {
    bool more = t < 15;
    if (more) stage(cur ^ 1, (t + 1) * 64);  // DMA hides under tile compute
    const f16* Kc = sm.kv.K[cur];
    const f16* Vc = sm.kv.V[cur];
    f32x16 sc0 = {}, sc1 = {};
#pragma unroll
    for (int kf = 0; kf < 4; ++kf) {
      int ch = (2 * kf + hi) ^ (l32 & 7);
      f16x8 k0 = *(const f16x8*)(Kc + l32 * 64 + ch * 8);
      sc0 = __builtin_amdgcn_mfma_f32_32x32x16_f16(k0, qf[kf], sc0, 0, 0, 0);
      f16x8 k1 = *(const f16x8*)(Kc + (32 + l32) * 64 + ch * 8);
      sc1 = __builtin_amdgcn_mfma_f32_32x32x16_f16(k1, qf[kf], sc1, 0, 0, 0);
    }
    float mx[16];
#pragma unroll
    for (int j = 0; j < 16; ++j) mx[j] = fmaxf(sc0[j], sc1[j]);
#pragma unroll
    for (int s = 8; s >= 1; s >>= 1)
#pragma unroll
      for (int j = 0; j < 8; ++j)
        if (j < s) mx[j] = fmaxf(mx[j], mx[j + s]);
#ifdef HAVE_PLSWAP
    float pmax;
    {
      float pa = mx[0], pb = mx[0];
      plswapf(pa, pb);  // pa/pb now hold {own-half, partner-half} pairs
      pmax = fmaxf(pa, pb);
    }
#else
    float pmax = fmaxf(mx[0], __shfl_xor(mx[0], 32));
#endif
    if (__any(pmax > m + 8.f)) {
      float mn = fmaxf(m, pmax);
      float c = fexp2(m - mn);
      lsum *= c;
#pragma unroll
      for (int j = 0; j < 16; ++j) { oacc0[j] *= c; oacc1[j] *= c; }
      m = mn;
    }
    unsigned w[8][2];
    float qs[8];
#pragma unroll
    for (int qd = 0; qd < 8; ++qd) {
      float a0, a1, a2, a3;
      if (qd < 4) {
        a0 = fexp2(sc0[qd * 4 + 0] - m); a1 = fexp2(sc0[qd * 4 + 1] - m);
        a2 = fexp2(sc0[qd * 4 + 2] - m); a3 = fexp2(sc0[qd * 4 + 3] - m);
      } else {
        a0 = fexp2(sc1[(qd - 4) * 4 + 0] - m); a1 = fexp2(sc1[(qd - 4) * 4 + 1] - m);
        a2 = fexp2(sc1[(qd - 4) * 4 + 2] - m); a3 = fexp2(sc1[(qd - 4) * 4 + 3] - m);
      }
      qs[qd] = (a0 + a1) + (a2 + a3);
      w[qd][0] = __builtin_bit_cast(unsigned, __builtin_amdgcn_cvt_pkrtz(a0, a1));
      w[qd][1] = __builtin_bit_cast(unsigned, __builtin_amdgcn_cvt_pkrtz(a2, a3));
    }
    lsum += ((qs[0] + qs[1]) + (qs[2] + qs[3])) + ((qs[4] + qs[5]) + (qs[6] + qs[7]));
#pragma unroll
    for (int kf = 0; kf < 4; ++kf) {
      int QB = (kf >> 1) * 4 + 2 * (kf & 1);
#ifdef HAVE_PLSWAP
      // new_a = {a.lo,b.lo} = lo-word frag; new_b = {a.hi,b.hi} = hi-word frag
      unsigned a0 = w[QB][0], b0 = w[QB + 1][0];
      unsigned a1 = w[QB][1], b1 = w[QB + 1][1];
      plswap(a0, b0);
      plswap(a1, b1);
      u32x4 pw = {a0, a1, b0, b1};
#else
      unsigned lo0, lo1, hi0, hi1;
      {
        unsigned s0 = hi ? w[QB][0] : w[QB + 1][0];
        unsigned s1 = hi ? w[QB][1] : w[QB + 1][1];
        unsigned r0 = __shfl_xor(s0, 32);
        unsigned r1 = __shfl_xor(s1, 32);
        lo0 = hi ? r0 : w[QB][0];
        lo1 = hi ? r1 : w[QB][1];
        hi0 = hi ? w[QB + 1][0] : r0;
        hi1 = hi ? w[QB + 1][1] : r1;
      }
      u32x4 pw = {lo0, lo1, hi0, hi1};
#endif
      f16x8 pf = __builtin_bit_cast(f16x8, pw);
      int ch = (2 * kf + hi) ^ (l32 & 7);
      f16x8 v0 = *(const f16x8*)(Vc + l32 * 64 + ch * 8);
      oacc0 = __builtin_amdgcn_mfma_f32_32x32x16_f16(v0, pf, oacc0, 0, 0, 0);
      f16x8 v1 = *(const f16x8*)(Vc + (32 + l32) * 64 + ch * 8);
      oacc1 = __builtin_amdgcn_mfma_f32_32x32x16_f16(v1, pf, oacc1, 0, 0, 0);
    }
    if (more) {
      __syncthreads();  // drains vmcnt -> next buf landed; readers done
      cur ^= 1;
    }
  }
#ifdef HAVE_PLSWAP
  float lt;
  {
    float sa = lsum, sb = lsum;
    plswapf(sa, sb);
    lt = sa + sb;
  }
#else
  float lt = lsum + __shfl_xor(lsum, 32);
#endif
  float inv = 1.f / lt;
  __syncthreads();
  float* Ow = sm.O + wid * (32 * 68) + l32 * 68;
#pragma unroll
  for (int dt = 0; dt < 2; ++dt) {
#pragma unroll
    for (int g = 0; g < 4; ++g) {
      int d0 = dt * 32 + g * 8 + hi * 4;
      f32x4 st;
      if (dt == 0) {
        st[0] = oacc0[g * 4 + 0] * inv; st[1] = oacc0[g * 4 + 1] * inv;
        st[2] = oacc0[g * 4 + 2] * inv; st[3] = oacc0[g * 4 + 3] * inv;
      } else {
        st[0] = oacc1[g * 4 + 0] * inv; st[1] = oacc1[g * 4 + 1] * inv;
        st[2] = oacc1[g * 4 + 2] * inv; st[3] = oacc1[g * 4 + 3] * inv;
      }
      *(f32x4*)(Ow + d0) = st;
    }
  }
  __syncthreads();
  int base_q = bb * 1024 + q0;
#pragma unroll
  for (int p = 0; p < 8; ++p) {
    int cl = p * 256 + tid;
    int row = cl >> 4, c = cl & 15;
    f32x4 v = *(const f32x4*)(sm.O + (row >> 5) * (32 * 68) + (row & 31) * 68 + c * 4);
    float4 bv4 = *(const float4*)(bvo + hh * 64 + c * 4);
    v[0] += bv4.x; v[1] += bv4.y; v[2] += bv4.z; v[3] += bv4.w;
    size_t off = (size_t)(base_q + row) * 768 + hh * 64 + c * 4;
    if (last) {
      *(f32x4*)(Fout + off) = v;
    } else {
      f16x4 hq;
      hq[0] = (f16)v[0]; hq[1] = (f16)v[1]; hq[2] = (f16)v[2]; hq[3] = (f16)v[3];
      *(f16x4*)(XhOut + off) = hq;
    }
  }
}

// ---------------------------------------------------------------------------
extern "C" void kernel_launch(void* const* d_in, const int* in_sizes, int n_in,
                              void* d_out, int out_size, void* d_ws,
                              size_t ws_size, hipStream_t stream) {
  const float* x = (const float*)d_in[0];
  const float* Wq = (const float*)d_in[1];
  const float* bq = (const float*)d_in[2];
  const float* Wk = (const float*)d_in[3];
  const float* bk = (const float*)d_in[4];
  const float* Wv = (const float*)d_in[5];
  const float* bv = (const float*)d_in[6];
  const float* Wo = (const float*)d_in[7];
  const float* bo = (const float*)d_in[8];
  float* out = (float*)d_out;

  char* ws = (char*)d_ws;
  size_t off = 0;
  auto alloc = [&](size_t bytes) -> void* {
    void* p = ws + off;
    off += (bytes + 255) & ~(size_t)255;
    return p;
  };
  f16* Wcat = (f16*)alloc((size_t)NQKV3 * ND * 2);  // 3.54 MB
  float* bvo = (float*)alloc(768 * 4);
  f16* Xh = (f16*)alloc((size_t)NM * ND * 2);   // 12.6 MB
  f16* Qb = (f16*)alloc((size_t)NM * ND * 2);   // B*H*S*HD
  f16* Kb = (f16*)alloc((size_t)NM * ND * 2);
  f16* Vtb = (f16*)alloc((size_t)NM * ND * 2);

  prep_weights<<<433, 256, 0, stream>>>(Wq, Wk, Wv, Wo, bv, bo, Wcat, bvo);
  x_to_f16<<<(NM * ND / 4) / 256, 256, 0, stream>>>(x, Xh);
  for (int l = 0; l < NLAYERS; ++l) {
    qkv_gemm<<<dim3(NM / 128, NQKV3 / 192), 256, 0, stream>>>(
        Xh, Wcat, bq, bk, Qb, Kb, Vtb);
    attn_fused<<<768, 256, 0, stream>>>(
        Qb, Kb, Vtb, bvo, Xh, out, l == NLAYERS - 1);
  }
}